// Round 8
// baseline (192.211 us; speedup 1.0000x reference)
//
#include <hip/hip_runtime.h>
#include <hip/hip_fp16.h>

typedef unsigned short u16;
typedef unsigned int   u32;

#define B_TOTAL 4096
#define NU      128
#define NS      64
#define NM      32
#define UNFOLDS 6
#define LOG2E   1.44269504088896340736f

__device__ __forceinline__ float bf2f(u16 v) {
  return __uint_as_float(((u32)v) << 16);
}
__device__ __forceinline__ u16 f2bf(float f) {  // RNE f32 -> bf16
  u32 x = __float_as_uint(f);
  return (u16)((x + 0x7fffu + ((x >> 16) & 1u)) >> 16);
}

template<bool BF16>
__device__ __forceinline__ float LD(const void* p, int i) {
  if (BF16) return bf2f(((const u16*)p)[i]);
  return ((const float*)p)[i];
}

__device__ __forceinline__ u32 pk(float a, float b) {  // (low=a, high=b) fp16 pair
  __half2 h = __halves2half2(__float2half_rn(a), __float2half_rn(b));
  return __builtin_bit_cast(u32, h);
}
__device__ __forceinline__ float lo2f(u32 h) {
  return __low2float(__builtin_bit_cast(__half2, h));
}
__device__ __forceinline__ float hi2f(u32 h) {
  return __high2float(__builtin_bit_cast(__half2, h));
}

// Dual-row step: one 16B record (sl01 f16x2, ms01 f16x2, w0 f32, w1 f32)
// feeds 4 sigmoids. 16B stride -> single ds_read_b128, shift-folded address.
// w kept in f32 (no unpack cvt; more precise than f16, closer to the f32
// reference); |w| free via the VOP3 abs input modifier on the denom FMA.
// Paired-rcp sigmoid r=rcp(p0*p1); s0=p1*r; s1=p0*r (rel ~1e-7; t<=~67 so
// p0*p1=inf only when both sigmoids ~0 -> rcp(inf)=0 -> s=0 exact).
// 26 full-rate VALU + 6 trans for 4 sigmoids.
__device__ __forceinline__ void step2f(uint4 a, float va, float vb,
                                       float& na0, float& da0, float& na1, float& da1,
                                       float& nb0, float& db0, float& nb1, float& db1) {
  float sl0 = lo2f(a.x), sl1 = hi2f(a.x);
  float ms0 = lo2f(a.y), ms1 = hi2f(a.y);
  float w0  = __uint_as_float(a.z);
  float w1  = __uint_as_float(a.w);
  float ta0 = fmaf(va, sl0, ms0);
  float ta1 = fmaf(va, sl1, ms1);
  float tb0 = fmaf(vb, sl0, ms0);
  float tb1 = fmaf(vb, sl1, ms1);
  float ea0 = __builtin_amdgcn_exp2f(ta0);
  float ea1 = __builtin_amdgcn_exp2f(ta1);
  float eb0 = __builtin_amdgcn_exp2f(tb0);
  float eb1 = __builtin_amdgcn_exp2f(tb1);
  float pa0 = 1.0f + ea0, pa1 = 1.0f + ea1;
  float pb0 = 1.0f + eb0, pb1 = 1.0f + eb1;
  float ra = __builtin_amdgcn_rcpf(pa0 * pa1);
  float rb = __builtin_amdgcn_rcpf(pb0 * pb1);
  float sa0 = pa1 * ra, sa1 = pa0 * ra;
  float sb0 = pb1 * rb, sb1 = pb0 * rb;
  na0 = fmaf(sa0, w0, na0);  da0 = fmaf(sa0, fabsf(w0), da0);
  na1 = fmaf(sa1, w1, na1);  da1 = fmaf(sa1, fabsf(w1), da1);
  nb0 = fmaf(sb0, w0, nb0);  db0 = fmaf(sb0, fabsf(w0), db0);
  nb1 = fmaf(sb1, w1, nb1);  db1 = fmaf(sb1, fabsf(w1), db1);
}

template<bool BF16>
__device__ __forceinline__ void body(
    const void* g_in, const void* g_state, const void* g_gleak, const void* g_vleak,
    const void* g_cm, const void* g_sigma, const void* g_mu, const void* g_w,
    const void* g_erev, const void* g_ssig, const void* g_smu, const void* g_sw,
    const void* g_serev, const void* g_mask, const void* g_smask,
    const void* g_iw, const void* g_ib, const void* g_ow, const void* g_ob,
    void* g_out,
    uint4* smT,     // 128 KB overlaid: sensory table first, then recurrent
    float* smV,     // 8 KB: per-pair v/x broadcast strips (2 rows x 128 f32)
    float* smP)     // 16 KB: per-pair partial-sum exchange (8 accs x 64 lanes)
{
  const int tid = threadIdx.x;           // 1024 threads = 16 waves
  const int b0  = blockIdx.x * 16;       // 16 rows per block

  const int wv  = tid >> 6;              // wave id 0..15
  const int u0  = tid & 63;
  const int u1  = u0 + 64;
  const int p   = wv & 7;                // row-pair id; waves p and p+8 share it
  const bool hiW = wv >= 8;              // hi wave: sources 64..127 / s 32..63
  const int ba = b0 + 2 * p;
  const int bb = ba + 1;

  float* vbA = smV + p * 256;            // row a strip (128 f32)
  float* vbB = vbA + 128;                // row b strip
  float* red = smP + p * 512;            // 8 accs x 64 lanes

  // ---- phase 1: stage sensory table (64 KB), stride 1024 ----
  #pragma unroll 4
  for (int e = tid; e < NS * 64; e += 1024) {
    int s = e >> 6, l = e & 63;
    int i0 = s * NU + l, i1 = i0 + 64;
    float sl0 = LD<BF16>(g_ssig, i0) * LOG2E, sl1 = LD<BF16>(g_ssig, i1) * LOG2E;
    float ms0 = LD<BF16>(g_smu, i0) * sl0,    ms1 = LD<BF16>(g_smu, i1) * sl1;
    float w0 = LD<BF16>(g_sw, i0) * LD<BF16>(g_smask, i0) * LD<BF16>(g_serev, i0);
    float w1 = LD<BF16>(g_sw, i1) * LD<BF16>(g_smask, i1) * LD<BF16>(g_serev, i1);
    smT[e] = make_uint4(pk(-sl0, -sl1), pk(ms0, ms1),
                        __float_as_uint(w0), __float_as_uint(w1));
  }

  // low wave of each pair owns the rows' x/v state (R3 asymmetric structure)
  float va0 = 0.f, va1 = 0.f, vb0 = 0.f, vb1 = 0.f;
  if (!hiW) {
    float iw = LD<BF16>(g_iw, u0), ib = LD<BF16>(g_ib, u0);
    float xa = LD<BF16>(g_in, ba * NS + u0) * iw + ib;
    float xb = LD<BF16>(g_in, bb * NS + u0) * iw + ib;
    va0 = LD<BF16>(g_state, ba * NU + u0);
    va1 = LD<BF16>(g_state, ba * NU + u1);
    vb0 = LD<BF16>(g_state, bb * NU + u0);
    vb1 = LD<BF16>(g_state, bb * NU + u1);
    vbA[u0] = xa;                        // stage x into the strips
    vbB[u0] = xb;
  }
  const float gl0 = LD<BF16>(g_gleak, u0), gl1 = LD<BF16>(g_gleak, u1);
  const float lk0 = gl0 * LD<BF16>(g_vleak, u0);
  const float lk1 = gl1 * LD<BF16>(g_vleak, u1);
  const float cm0 = LD<BF16>(g_cm, u0) * (float)UNFOLDS;
  const float cm1 = LD<BF16>(g_cm, u1) * (float)UNFOLDS;
  const float cgl0 = cm0 + gl0 + 1e-8f;
  const float cgl1 = cm1 + gl1 + 1e-8f;

  const uint4* pR = smT + u0;
  const int sbase = hiW ? 32 : 0;        // sensory half for this wave
  const int jbase = hiW ? 64 : 0;        // recurrent source half

  __syncthreads();   // table + x strips visible to all

  // ---- sensory partials (32 sources per wave); broadcast x via LDS ----
  float nsa0 = 0.f, dsa0 = 0.f, nsa1 = 0.f, dsa1 = 0.f;
  float nsb0 = 0.f, dsb0 = 0.f, nsb1 = 0.f, dsb1 = 0.f;
  #pragma unroll 8
  for (int s4 = 0; s4 < 32; s4 += 4) {
    float4 xa4 = *(const float4*)(vbA + sbase + s4);   // uniform -> broadcast
    float4 xb4 = *(const float4*)(vbB + sbase + s4);
    step2f(pR[(sbase + s4 + 0) * 64], xa4.x, xb4.x, nsa0, dsa0, nsa1, dsa1, nsb0, dsb0, nsb1, dsb1);
    step2f(pR[(sbase + s4 + 1) * 64], xa4.y, xb4.y, nsa0, dsa0, nsa1, dsa1, nsb0, dsb0, nsb1, dsb1);
    step2f(pR[(sbase + s4 + 2) * 64], xa4.z, xb4.z, nsa0, dsa0, nsa1, dsa1, nsb0, dsb0, nsb1, dsb1);
    step2f(pR[(sbase + s4 + 3) * 64], xa4.w, xb4.w, nsa0, dsa0, nsa1, dsa1, nsb0, dsb0, nsb1, dsb1);
  }
  __syncthreads();   // everyone done reading x strips + sensory table

  // publish initial v into the strips (low waves own v)
  if (!hiW) {
    vbA[u0] = va0;  vbA[u1] = va1;
    vbB[u0] = vb0;  vbB[u1] = vb1;
  }

  // ---- phase 2: stage recurrent table (128 KB) over the same region ----
  #pragma unroll 4
  for (int e = tid; e < NU * 64; e += 1024) {
    int j = e >> 6, l = e & 63;
    int i0 = j * NU + l, i1 = i0 + 64;
    float sl0 = LD<BF16>(g_sigma, i0) * LOG2E, sl1 = LD<BF16>(g_sigma, i1) * LOG2E;
    float ms0 = LD<BF16>(g_mu, i0) * sl0,      ms1 = LD<BF16>(g_mu, i1) * sl1;
    float w0 = LD<BF16>(g_w, i0) * LD<BF16>(g_mask, i0) * LD<BF16>(g_erev, i0);
    float w1 = LD<BF16>(g_w, i1) * LD<BF16>(g_mask, i1) * LD<BF16>(g_erev, i1);
    smT[e] = make_uint4(pk(-sl0, -sl1), pk(ms0, ms1),
                        __float_as_uint(w0), __float_as_uint(w1));
  }
  __syncthreads();   // table + v strips visible

  // ---- ODE unfolds: each wave does 64 sources, then pair-reduce ----
  #pragma unroll 1
  for (int it = 0; it < UNFOLDS; ++it) {
    float na0 = nsa0, da0 = dsa0, na1 = nsa1, da1 = dsa1;
    float nb0 = nsb0, db0 = dsb0, nb1 = nsb1, db1 = dsb1;
    #pragma unroll 8
    for (int j4 = 0; j4 < 64; j4 += 4) {
      float4 va4 = *(const float4*)(vbA + jbase + j4);  // uniform -> broadcast
      float4 vb4 = *(const float4*)(vbB + jbase + j4);
      step2f(pR[(jbase + j4 + 0) * 64], va4.x, vb4.x, na0, da0, na1, da1, nb0, db0, nb1, db1);
      step2f(pR[(jbase + j4 + 1) * 64], va4.y, vb4.y, na0, da0, na1, da1, nb0, db0, nb1, db1);
      step2f(pR[(jbase + j4 + 2) * 64], va4.z, vb4.z, na0, da0, na1, da1, nb0, db0, nb1, db1);
      step2f(pR[(jbase + j4 + 3) * 64], va4.w, vb4.w, na0, da0, na1, da1, nb0, db0, nb1, db1);
    }
    if (hiW) {       // hi wave publishes its partials
      red[0 * 64 + u0] = na0;  red[1 * 64 + u0] = da0;
      red[2 * 64 + u0] = na1;  red[3 * 64 + u0] = da1;
      red[4 * 64 + u0] = nb0;  red[5 * 64 + u0] = db0;
      red[6 * 64 + u0] = nb1;  red[7 * 64 + u0] = db1;
    }
    __syncthreads();
    if (!hiW) {      // low wave reduces, updates v, republishes strips
      na0 += red[0 * 64 + u0];  da0 += red[1 * 64 + u0];
      na1 += red[2 * 64 + u0];  da1 += red[3 * 64 + u0];
      nb0 += red[4 * 64 + u0];  db0 += red[5 * 64 + u0];
      nb1 += red[6 * 64 + u0];  db1 += red[7 * 64 + u0];
      va0 = fmaf(cm0, va0, lk0 + na0) * __builtin_amdgcn_rcpf(cgl0 + da0);
      va1 = fmaf(cm1, va1, lk1 + na1) * __builtin_amdgcn_rcpf(cgl1 + da1);
      vb0 = fmaf(cm0, vb0, lk0 + nb0) * __builtin_amdgcn_rcpf(cgl0 + db0);
      vb1 = fmaf(cm1, vb1, lk1 + nb1) * __builtin_amdgcn_rcpf(cgl1 + db1);
      if (it < UNFOLDS - 1) {
        vbA[u0] = va0;  vbA[u1] = va1;
        vbB[u0] = vb0;  vbB[u1] = vb1;
      }
    }
    __syncthreads();
  }

  // ---- epilogue (low waves only): out[B,M] then v[B,U] ----
  if (!hiW) {
    if (BF16) {
      u16* om = (u16*)g_out;
      u16* ov = om + B_TOTAL * NM;
      ov[ba * NU + u0] = f2bf(va0);
      ov[ba * NU + u1] = f2bf(va1);
      ov[bb * NU + u0] = f2bf(vb0);
      ov[bb * NU + u1] = f2bf(vb1);
      if (u0 < NM) {
        float ow = LD<true>(g_ow, u0), ob = LD<true>(g_ob, u0);
        om[ba * NM + u0] = f2bf(fmaf(va0, ow, ob));
        om[bb * NM + u0] = f2bf(fmaf(vb0, ow, ob));
      }
    } else {
      float* om = (float*)g_out;
      float* ov = om + B_TOTAL * NM;
      ov[ba * NU + u0] = va0;
      ov[ba * NU + u1] = va1;
      ov[bb * NU + u0] = vb0;
      ov[bb * NU + u1] = vb1;
      if (u0 < NM) {
        float ow = LD<false>(g_ow, u0), ob = LD<false>(g_ob, u0);
        om[ba * NM + u0] = fmaf(va0, ow, ob);
        om[bb * NM + u0] = fmaf(vb0, ow, ob);
      }
    }
  }
}

__global__ __launch_bounds__(1024, 4) void ltc_kernel(
    const void* g_in, const void* g_state, const void* g_gleak, const void* g_vleak,
    const void* g_cm, const void* g_sigma, const void* g_mu, const void* g_w,
    const void* g_erev, const void* g_ssig, const void* g_smu, const void* g_sw,
    const void* g_serev, const void* g_mask, const void* g_smask,
    const void* g_iw, const void* g_ib, const void* g_ow, const void* g_ob,
    void* g_out)
{
  // 128 KB overlaid region: sensory (64 KB) then recurrent (128 KB)
  __shared__ uint4 smT[NU * 64];
  // 8 KB: 8 pairs x 2 rows x 128 f32 broadcast strips
  __shared__ float smV[8 * 256];
  // 16 KB: 8 pairs x 8 accs x 64 lanes partial-sum exchange
  __shared__ float smP[8 * 512];

  // runtime dtype probe: sigma in [3,8]; bf16 -> even u16s decode in-range
  const u16* sg = (const u16*)g_sigma;
  int cnt = 0;
  #pragma unroll
  for (int i = 0; i < 32; ++i) {
    float f = bf2f(sg[2 * i]);
    cnt += (f >= 2.0f && f <= 16.0f) ? 1 : 0;
  }
  if (cnt >= 24)
    body<true >(g_in, g_state, g_gleak, g_vleak, g_cm, g_sigma, g_mu, g_w, g_erev,
                g_ssig, g_smu, g_sw, g_serev, g_mask, g_smask,
                g_iw, g_ib, g_ow, g_ob, g_out, smT, smV, smP);
  else
    body<false>(g_in, g_state, g_gleak, g_vleak, g_cm, g_sigma, g_mu, g_w, g_erev,
                g_ssig, g_smu, g_sw, g_serev, g_mask, g_smask,
                g_iw, g_ib, g_ow, g_ob, g_out, smT, smV, smP);
}

extern "C" void kernel_launch(void* const* d_in, const int* in_sizes, int n_in,
                              void* d_out, int out_size, void* d_ws, size_t ws_size,
                              hipStream_t stream) {
  (void)in_sizes; (void)n_in; (void)out_size; (void)d_ws; (void)ws_size;
  dim3 grid(B_TOTAL / 16);   // 256 blocks = 1 per CU
  dim3 block(1024);          // 16 waves: pair (p, p+8) splits sources for 2 rows
  hipLaunchKernelGGL(ltc_kernel, grid, block, 0, stream,
                     d_in[0], d_in[1], d_in[2], d_in[3], d_in[4],
                     d_in[5], d_in[6], d_in[7], d_in[8],
                     d_in[9], d_in[10], d_in[11], d_in[12],
                     d_in[13], d_in[14], d_in[15], d_in[16],
                     d_in[17], d_in[18], d_out);
}

// Round 9
// 188.251 us; speedup vs baseline: 1.0210x; 1.0210x over previous
//
#include <hip/hip_runtime.h>
#include <hip/hip_fp16.h>

typedef unsigned short u16;
typedef unsigned int   u32;

#define B_TOTAL 4096
#define NU      128
#define NS      64
#define NM      32
#define UNFOLDS 6
#define LOG2E   1.44269504088896340736f

__device__ __forceinline__ float bf2f(u16 v) {
  return __uint_as_float(((u32)v) << 16);
}
__device__ __forceinline__ u16 f2bf(float f) {  // RNE f32 -> bf16
  u32 x = __float_as_uint(f);
  return (u16)((x + 0x7fffu + ((x >> 16) & 1u)) >> 16);
}

template<bool BF16>
__device__ __forceinline__ float LD(const void* p, int i) {
  if (BF16) return bf2f(((const u16*)p)[i]);
  return ((const float*)p)[i];
}

__device__ __forceinline__ u32 pk(float a, float b) {  // (low=a, high=b) fp16 pair
  __half2 h = __halves2half2(__float2half_rn(a), __float2half_rn(b));
  return __builtin_bit_cast(u32, h);
}
__device__ __forceinline__ float lo2f(u32 h) {
  return __low2float(__builtin_bit_cast(__half2, h));
}
__device__ __forceinline__ float hi2f(u32 h) {
  return __high2float(__builtin_bit_cast(__half2, h));
}

// Dual-row step: one 16B record (sl01 f16x2, ms01 f16x2, w0 f32, w1 f32)
// feeds 4 sigmoids. 16B stride -> single ds_read_b128, shift-folded address.
// w kept in f32 (no unpack cvt; more precise than f16, closer to the f32
// reference); |w| free via the VOP3 abs input modifier on the denom FMA.
// Paired-rcp sigmoid r=rcp(p0*p1); s0=p1*r; s1=p0*r (rel ~1e-7; t<=~67 so
// p0*p1=inf only when both sigmoids ~0 -> rcp(inf)=0 -> s=0 exact).
// 26 full-rate VALU + 6 trans for 4 sigmoids.
__device__ __forceinline__ void step2f(uint4 a, float va, float vb,
                                       float& na0, float& da0, float& na1, float& da1,
                                       float& nb0, float& db0, float& nb1, float& db1) {
  float sl0 = lo2f(a.x), sl1 = hi2f(a.x);
  float ms0 = lo2f(a.y), ms1 = hi2f(a.y);
  float w0  = __uint_as_float(a.z);
  float w1  = __uint_as_float(a.w);
  float ta0 = fmaf(va, sl0, ms0);
  float ta1 = fmaf(va, sl1, ms1);
  float tb0 = fmaf(vb, sl0, ms0);
  float tb1 = fmaf(vb, sl1, ms1);
  float ea0 = __builtin_amdgcn_exp2f(ta0);
  float ea1 = __builtin_amdgcn_exp2f(ta1);
  float eb0 = __builtin_amdgcn_exp2f(tb0);
  float eb1 = __builtin_amdgcn_exp2f(tb1);
  float pa0 = 1.0f + ea0, pa1 = 1.0f + ea1;
  float pb0 = 1.0f + eb0, pb1 = 1.0f + eb1;
  float ra = __builtin_amdgcn_rcpf(pa0 * pa1);
  float rb = __builtin_amdgcn_rcpf(pb0 * pb1);
  float sa0 = pa1 * ra, sa1 = pa0 * ra;
  float sb0 = pb1 * rb, sb1 = pb0 * rb;
  na0 = fmaf(sa0, w0, na0);  da0 = fmaf(sa0, fabsf(w0), da0);
  na1 = fmaf(sa1, w1, na1);  da1 = fmaf(sa1, fabsf(w1), da1);
  nb0 = fmaf(sb0, w0, nb0);  db0 = fmaf(sb0, fabsf(w0), db0);
  nb1 = fmaf(sb1, w1, nb1);  db1 = fmaf(sb1, fabsf(w1), db1);
}

template<bool BF16>
__device__ __forceinline__ void body(
    const void* g_in, const void* g_state, const void* g_gleak, const void* g_vleak,
    const void* g_cm, const void* g_sigma, const void* g_mu, const void* g_w,
    const void* g_erev, const void* g_ssig, const void* g_smu, const void* g_sw,
    const void* g_serev, const void* g_mask, const void* g_smask,
    const void* g_iw, const void* g_ib, const void* g_ow, const void* g_ob,
    void* g_out,
    uint4* smT,     // 128 KB overlaid: sensory table first, then recurrent
    float* smV,     // 8 KB: per-pair v/x broadcast strips (2 rows x 128 f32)
    float* smP)     // 16 KB: per-pair partial-sum exchange (8 accs x 64 lanes)
{
  const int tid = threadIdx.x;           // 1024 threads = 16 waves
  const int b0  = blockIdx.x * 16;       // 16 rows per block

  const int wv  = tid >> 6;              // wave id 0..15
  const int u0  = tid & 63;
  const int u1  = u0 + 64;
  const int p   = wv & 7;                // row-pair id; waves p and p+8 share it
  const bool hiW = wv >= 8;              // hi wave: sources 64..127 / s 32..63
  const int ba = b0 + 2 * p;
  const int bb = ba + 1;

  float* vbA = smV + p * 256;            // row a strip (128 f32)
  float* vbB = vbA + 128;                // row b strip
  float* red = smP + p * 512;            // 8 accs x 64 lanes

  // ---- phase 1: stage sensory table (64 KB), stride 1024 ----
  #pragma unroll 4
  for (int e = tid; e < NS * 64; e += 1024) {
    int s = e >> 6, l = e & 63;
    int i0 = s * NU + l, i1 = i0 + 64;
    float sl0 = LD<BF16>(g_ssig, i0) * LOG2E, sl1 = LD<BF16>(g_ssig, i1) * LOG2E;
    float ms0 = LD<BF16>(g_smu, i0) * sl0,    ms1 = LD<BF16>(g_smu, i1) * sl1;
    float w0 = LD<BF16>(g_sw, i0) * LD<BF16>(g_smask, i0) * LD<BF16>(g_serev, i0);
    float w1 = LD<BF16>(g_sw, i1) * LD<BF16>(g_smask, i1) * LD<BF16>(g_serev, i1);
    smT[e] = make_uint4(pk(-sl0, -sl1), pk(ms0, ms1),
                        __float_as_uint(w0), __float_as_uint(w1));
  }

  // low wave of each pair owns the rows' x/v state (R3 asymmetric structure)
  float va0 = 0.f, va1 = 0.f, vb0 = 0.f, vb1 = 0.f;
  if (!hiW) {
    float iw = LD<BF16>(g_iw, u0), ib = LD<BF16>(g_ib, u0);
    float xa = LD<BF16>(g_in, ba * NS + u0) * iw + ib;
    float xb = LD<BF16>(g_in, bb * NS + u0) * iw + ib;
    va0 = LD<BF16>(g_state, ba * NU + u0);
    va1 = LD<BF16>(g_state, ba * NU + u1);
    vb0 = LD<BF16>(g_state, bb * NU + u0);
    vb1 = LD<BF16>(g_state, bb * NU + u1);
    vbA[u0] = xa;                        // stage x into the strips
    vbB[u0] = xb;
  }
  const float gl0 = LD<BF16>(g_gleak, u0), gl1 = LD<BF16>(g_gleak, u1);
  const float lk0 = gl0 * LD<BF16>(g_vleak, u0);
  const float lk1 = gl1 * LD<BF16>(g_vleak, u1);
  const float cm0 = LD<BF16>(g_cm, u0) * (float)UNFOLDS;
  const float cm1 = LD<BF16>(g_cm, u1) * (float)UNFOLDS;
  const float cgl0 = cm0 + gl0 + 1e-8f;
  const float cgl1 = cm1 + gl1 + 1e-8f;

  const uint4* pR = smT + u0;
  const int sbase = hiW ? 32 : 0;        // sensory half for this wave
  const int jbase = hiW ? 64 : 0;        // recurrent source half

  __syncthreads();   // table + x strips visible to all

  // ---- sensory partials (32 sources per wave); broadcast x via LDS ----
  float nsa0 = 0.f, dsa0 = 0.f, nsa1 = 0.f, dsa1 = 0.f;
  float nsb0 = 0.f, dsb0 = 0.f, nsb1 = 0.f, dsb1 = 0.f;
  #pragma unroll 4
  for (int s4 = 0; s4 < 32; s4 += 4) {
    float4 xa4 = *(const float4*)(vbA + sbase + s4);   // uniform -> broadcast
    float4 xb4 = *(const float4*)(vbB + sbase + s4);
    step2f(pR[(sbase + s4 + 0) * 64], xa4.x, xb4.x, nsa0, dsa0, nsa1, dsa1, nsb0, dsb0, nsb1, dsb1);
    step2f(pR[(sbase + s4 + 1) * 64], xa4.y, xb4.y, nsa0, dsa0, nsa1, dsa1, nsb0, dsb0, nsb1, dsb1);
    step2f(pR[(sbase + s4 + 2) * 64], xa4.z, xb4.z, nsa0, dsa0, nsa1, dsa1, nsb0, dsb0, nsb1, dsb1);
    step2f(pR[(sbase + s4 + 3) * 64], xa4.w, xb4.w, nsa0, dsa0, nsa1, dsa1, nsb0, dsb0, nsb1, dsb1);
  }
  __syncthreads();   // everyone done reading x strips + sensory table

  // publish initial v into the strips (low waves own v)
  if (!hiW) {
    vbA[u0] = va0;  vbA[u1] = va1;
    vbB[u0] = vb0;  vbB[u1] = vb1;
  }

  // ---- phase 2: stage recurrent table (128 KB) over the same region ----
  #pragma unroll 4
  for (int e = tid; e < NU * 64; e += 1024) {
    int j = e >> 6, l = e & 63;
    int i0 = j * NU + l, i1 = i0 + 64;
    float sl0 = LD<BF16>(g_sigma, i0) * LOG2E, sl1 = LD<BF16>(g_sigma, i1) * LOG2E;
    float ms0 = LD<BF16>(g_mu, i0) * sl0,      ms1 = LD<BF16>(g_mu, i1) * sl1;
    float w0 = LD<BF16>(g_w, i0) * LD<BF16>(g_mask, i0) * LD<BF16>(g_erev, i0);
    float w1 = LD<BF16>(g_w, i1) * LD<BF16>(g_mask, i1) * LD<BF16>(g_erev, i1);
    smT[e] = make_uint4(pk(-sl0, -sl1), pk(ms0, ms1),
                        __float_as_uint(w0), __float_as_uint(w1));
  }
  __syncthreads();   // table + v strips visible

  // ---- ODE unfolds: each wave does 64 sources, then pair-reduce ----
  #pragma unroll 1
  for (int it = 0; it < UNFOLDS; ++it) {
    float na0 = nsa0, da0 = dsa0, na1 = nsa1, da1 = dsa1;
    float nb0 = nsb0, db0 = dsb0, nb1 = nsb1, db1 = dsb1;
    #pragma unroll 4
    for (int j4 = 0; j4 < 64; j4 += 4) {
      float4 va4 = *(const float4*)(vbA + jbase + j4);  // uniform -> broadcast
      float4 vb4 = *(const float4*)(vbB + jbase + j4);
      step2f(pR[(jbase + j4 + 0) * 64], va4.x, vb4.x, na0, da0, na1, da1, nb0, db0, nb1, db1);
      step2f(pR[(jbase + j4 + 1) * 64], va4.y, vb4.y, na0, da0, na1, da1, nb0, db0, nb1, db1);
      step2f(pR[(jbase + j4 + 2) * 64], va4.z, vb4.z, na0, da0, na1, da1, nb0, db0, nb1, db1);
      step2f(pR[(jbase + j4 + 3) * 64], va4.w, vb4.w, na0, da0, na1, da1, nb0, db0, nb1, db1);
    }
    if (hiW) {       // hi wave publishes its partials
      red[0 * 64 + u0] = na0;  red[1 * 64 + u0] = da0;
      red[2 * 64 + u0] = na1;  red[3 * 64 + u0] = da1;
      red[4 * 64 + u0] = nb0;  red[5 * 64 + u0] = db0;
      red[6 * 64 + u0] = nb1;  red[7 * 64 + u0] = db1;
    }
    __syncthreads();
    if (!hiW) {      // low wave reduces, updates v, republishes strips
      na0 += red[0 * 64 + u0];  da0 += red[1 * 64 + u0];
      na1 += red[2 * 64 + u0];  da1 += red[3 * 64 + u0];
      nb0 += red[4 * 64 + u0];  db0 += red[5 * 64 + u0];
      nb1 += red[6 * 64 + u0];  db1 += red[7 * 64 + u0];
      va0 = fmaf(cm0, va0, lk0 + na0) * __builtin_amdgcn_rcpf(cgl0 + da0);
      va1 = fmaf(cm1, va1, lk1 + na1) * __builtin_amdgcn_rcpf(cgl1 + da1);
      vb0 = fmaf(cm0, vb0, lk0 + nb0) * __builtin_amdgcn_rcpf(cgl0 + db0);
      vb1 = fmaf(cm1, vb1, lk1 + nb1) * __builtin_amdgcn_rcpf(cgl1 + db1);
      if (it < UNFOLDS - 1) {
        vbA[u0] = va0;  vbA[u1] = va1;
        vbB[u0] = vb0;  vbB[u1] = vb1;
      }
    }
    __syncthreads();
  }

  // ---- epilogue (low waves only): out[B,M] then v[B,U] ----
  if (!hiW) {
    if (BF16) {
      u16* om = (u16*)g_out;
      u16* ov = om + B_TOTAL * NM;
      ov[ba * NU + u0] = f2bf(va0);
      ov[ba * NU + u1] = f2bf(va1);
      ov[bb * NU + u0] = f2bf(vb0);
      ov[bb * NU + u1] = f2bf(vb1);
      if (u0 < NM) {
        float ow = LD<true>(g_ow, u0), ob = LD<true>(g_ob, u0);
        om[ba * NM + u0] = f2bf(fmaf(va0, ow, ob));
        om[bb * NM + u0] = f2bf(fmaf(vb0, ow, ob));
      }
    } else {
      float* om = (float*)g_out;
      float* ov = om + B_TOTAL * NM;
      ov[ba * NU + u0] = va0;
      ov[ba * NU + u1] = va1;
      ov[bb * NU + u0] = vb0;
      ov[bb * NU + u1] = vb1;
      if (u0 < NM) {
        float ow = LD<false>(g_ow, u0), ob = LD<false>(g_ob, u0);
        om[ba * NM + u0] = fmaf(va0, ow, ob);
        om[bb * NM + u0] = fmaf(vb0, ow, ob);
      }
    }
  }
}

__global__ __launch_bounds__(1024, 4) void ltc_kernel(
    const void* g_in, const void* g_state, const void* g_gleak, const void* g_vleak,
    const void* g_cm, const void* g_sigma, const void* g_mu, const void* g_w,
    const void* g_erev, const void* g_ssig, const void* g_smu, const void* g_sw,
    const void* g_serev, const void* g_mask, const void* g_smask,
    const void* g_iw, const void* g_ib, const void* g_ow, const void* g_ob,
    void* g_out)
{
  // 128 KB overlaid region: sensory (64 KB) then recurrent (128 KB)
  __shared__ uint4 smT[NU * 64];
  // 8 KB: 8 pairs x 2 rows x 128 f32 broadcast strips
  __shared__ float smV[8 * 256];
  // 16 KB: 8 pairs x 8 accs x 64 lanes partial-sum exchange
  __shared__ float smP[8 * 512];

  // runtime dtype probe: sigma in [3,8]; bf16 -> even u16s decode in-range
  const u16* sg = (const u16*)g_sigma;
  int cnt = 0;
  #pragma unroll
  for (int i = 0; i < 32; ++i) {
    float f = bf2f(sg[2 * i]);
    cnt += (f >= 2.0f && f <= 16.0f) ? 1 : 0;
  }
  if (cnt >= 24)
    body<true >(g_in, g_state, g_gleak, g_vleak, g_cm, g_sigma, g_mu, g_w, g_erev,
                g_ssig, g_smu, g_sw, g_serev, g_mask, g_smask,
                g_iw, g_ib, g_ow, g_ob, g_out, smT, smV, smP);
  else
    body<false>(g_in, g_state, g_gleak, g_vleak, g_cm, g_sigma, g_mu, g_w, g_erev,
                g_ssig, g_smu, g_sw, g_serev, g_mask, g_smask,
                g_iw, g_ib, g_ow, g_ob, g_out, smT, smV, smP);
}

extern "C" void kernel_launch(void* const* d_in, const int* in_sizes, int n_in,
                              void* d_out, int out_size, void* d_ws, size_t ws_size,
                              hipStream_t stream) {
  (void)in_sizes; (void)n_in; (void)out_size; (void)d_ws; (void)ws_size;
  dim3 grid(B_TOTAL / 16);   // 256 blocks = 1 per CU
  dim3 block(1024);          // 16 waves: pair (p, p+8) splits sources for 2 rows
  hipLaunchKernelGGL(ltc_kernel, grid, block, 0, stream,
                     d_in[0], d_in[1], d_in[2], d_in[3], d_in[4],
                     d_in[5], d_in[6], d_in[7], d_in[8],
                     d_in[9], d_in[10], d_in[11], d_in[12],
                     d_in[13], d_in[14], d_in[15], d_in[16],
                     d_in[17], d_in[18], d_out);
}